// Round 12
// baseline (175.932 us; speedup 1.0000x reference)
//
#include <hip/hip_runtime.h>

#define NNODES 100000
#define NEDGES 1600000
#define DIM 64
#define NB 782          // buckets of 128 nodes (dst >> 7); 782*128 = 100096
#define NPB 256         // partition blocks
#define CHUNK 6250      // edges per partition block (NPB * CHUNK == NEDGES)
#define NCONV 391       // convert blocks (391*1024*4 = 1,601,536 >= 1.6M float4)
#define CAP 3968        // padded slots per bucket (mean 2048, sigma 45 -> 42 sigma)
#define HP 68           // hbuf pitch in SHORTS (64 + 4 pad)
#define NTILES 6250     // 100000 / 16 row-tiles

typedef __attribute__((ext_vector_type(4))) float f32x4;
typedef __attribute__((ext_vector_type(8))) short s16x8;   // 8 bf16 in 4 VGPRs

__device__ __forceinline__ unsigned short bf16_rne(float f) {
  unsigned u = __float_as_uint(f);
  u += 0x7FFF + ((u >> 16) & 1);
  return (unsigned short)(u >> 16);
}
__device__ __forceinline__ float bf16_to_f32(unsigned short h) {
  return __uint_as_float(((unsigned)h) << 16);
}

// ---------------- P0: heterogeneous build kernel ----------------------------
// blocks [0,NPB): partition edges into padded buckets (coalesced flush)
// blocks [NPB,NPB+NCONV): convert x -> bf16 table (overlaps partition latency)
// block NPB+NCONV: pack W1/W2 into MFMA B-frag layout
__global__ __launch_bounds__(1024) void build_kernel(
    const float* __restrict__ x, const int* __restrict__ ei,
    int* __restrict__ gcursor, unsigned short* __restrict__ xb,
    int* __restrict__ bpart,
    const float* __restrict__ W1, const float* __restrict__ W2,
    unsigned short* __restrict__ Wp1, unsigned short* __restrict__ Wp2) {
  int t = threadIdx.x;
  int bid = blockIdx.x;
  if (bid < NPB) {
    __shared__ int sd[1024];                // hist -> scan
    __shared__ int delta[1024];             // global_base - local_start
    __shared__ int lcur[1024];              // local scatter cursor
    __shared__ int stage[CHUNK];            // bucket-sorted packed edges
    __shared__ unsigned short sbuck[CHUNK]; // bucket id per staged slot
    __shared__ int wsum[16];
    sd[t] = 0;
    __syncthreads();
    int base = bid * CHUNK;
    int vals[7], bks[7];                    // edges held in registers
#pragma unroll
    for (int k = 0; k < 7; ++k) {
      int i = t + k * 1024;
      if (i < CHUNK) {
        int s = ei[base + i];
        int d = ei[NEDGES + base + i];
        int b = d >> 7;
        vals[k] = ((d & 127) << 17) | s;    // src < 2^17, dlow bits 17..23
        bks[k] = b;
        atomicAdd(&sd[b], 1);
      }
    }
    __syncthreads();
    // shuffle-based inclusive scan of 1024 entries (3 barriers total)
    int v = sd[t];
    int lane = t & 63, wv = t >> 6;
    int sv = v;
#pragma unroll
    for (int off = 1; off < 64; off <<= 1) {
      int o = __shfl_up(sv, off);
      if (lane >= off) sv += o;
    }
    if (lane == 63) wsum[wv] = sv;
    __syncthreads();
    if (wv == 0 && lane < 16) {
      int w = wsum[lane];
#pragma unroll
      for (int off = 1; off < 16; off <<= 1) {
        int o = __shfl_up(w, off);
        if (lane >= off) w += o;
      }
      wsum[lane] = w;
    }
    __syncthreads();
    int incl = sv + (wv ? wsum[wv - 1] : 0);
    int excl = incl - v;                    // local run start
    delta[t] = (v ? (t * CAP + atomicAdd(&gcursor[t], v)) : 0) - excl;
    lcur[t] = excl;
    __syncthreads();
#pragma unroll
    for (int k = 0; k < 7; ++k) {
      int i = t + k * 1024;
      if (i < CHUNK) {
        int p = atomicAdd(&lcur[bks[k]], 1);
        stage[p] = vals[k];
        sbuck[p] = (unsigned short)bks[k];
      }
    }
    __syncthreads();
    // flush: consecutive i -> consecutive global addresses within each run
    for (int i = t; i < CHUNK; i += 1024)
      bpart[delta[sbuck[i]] + i] = stage[i];
  } else if (bid < NPB + NCONV) {
    int cb = bid - NPB;
#pragma unroll
    for (int j = 0; j < 4; ++j) {
      int i = cb * 4096 + j * 1024 + t;
      if (i < NNODES * DIM / 4) {
        float4 vv = ((const float4*)x)[i];
        ushort4 o;
        o.x = bf16_rne(vv.x); o.y = bf16_rne(vv.y);
        o.z = bf16_rne(vv.z); o.w = bf16_rne(vv.w);
        ((ushort4*)xb)[i] = o;
      }
    }
  } else {
    // pack W1/W2: lane L holds B[k=8*(L>>4)+j][n=L&15] per (kk,nt) sub-tile
    if (t < 128) {
      int lane = t & 63;
      const float* W = (t >= 64) ? W2 : W1;
      unsigned short* Wp = (t >= 64) ? Wp2 : Wp1;
      int q = lane >> 4, n16 = lane & 15;
#pragma unroll
      for (int f = 0; f < 8; ++f) {
        int kk = f >> 2, nt = f & 3;
#pragma unroll
        for (int j = 0; j < 8; ++j) {
          int k = kk * 32 + q * 8 + j;
          int n = nt * 16 + n16;
          Wp[f * 512 + lane * 8 + j] = bf16_rne(W[k * DIM + n]);
        }
      }
    }
  }
}

// ---------------- P2 MEGA: sort + gather + GEMM1 + BN-stats partials --------
// block = one bucket of 128 nodes (8 MFMA row-tiles), 512 threads (8 waves).
__global__ __launch_bounds__(512, 8) void mega_kernel(
    const int* __restrict__ bpart, const int* __restrict__ gcursor,
    const unsigned short* __restrict__ xb, float* __restrict__ h1,
    const unsigned short* __restrict__ Wp, const float* __restrict__ b1,
    const float* __restrict__ epsp,
    float* __restrict__ sums, float* __restrict__ sumsq) {
  __shared__ int sd[128];        // per-node degree -> inclusive scan
  __shared__ int cur[128];       // scatter cursors
  __shared__ int stage[CAP];     // sorted src list for this bucket
  __shared__ unsigned short hbuf[128 * HP];  // gathered agg rows, bf16
  __shared__ float lsum[DIM];
  __shared__ float lsq[DIM];
  int b = blockIdx.x;
  int t = threadIdx.x;
  if (t < 128) sd[t] = 0;
  if (t < DIM) { lsum[t] = 0.0f; lsq[t] = 0.0f; }
  __syncthreads();
  int pbase = b * CAP;
  int cnt = gcursor[b];                     // zero-based cursor == count
  // --- phase A: counting sort into LDS stage ---
  for (int i = t; i < cnt; i += 512)
    atomicAdd(&sd[bpart[pbase + i] >> 17], 1);
  __syncthreads();
  int deg = (t < 128) ? sd[t] : 0;
  for (int off = 1; off < 128; off <<= 1) {   // inclusive scan of degrees
    int a = (t < 128 && t >= off) ? sd[t - off] : 0;
    __syncthreads();
    if (t < 128) sd[t] += a;
    __syncthreads();
  }
  if (t < 128) cur[t] = sd[t] - deg;          // exclusive start
  __syncthreads();
  for (int i = t; i < cnt; i += 512) {
    int v = bpart[pbase + i];
    int p = atomicAdd(&cur[v >> 17], 1);
    stage[p] = v & 0x1FFFF;
  }
  __syncthreads();
  // --- phase B: gather neighbor rows (bf16) into hbuf (bf16), ILP=8 ---
  {
    int part = t & 15;
    int ng = t >> 4;                          // 0..31
#pragma unroll 1
    for (int pass = 0; pass < 4; ++pass) {
      int nl = ng + pass * 32;                // local node 0..127
      int e0 = (nl == 0) ? 0 : sd[nl - 1];
      int e1 = sd[nl];
      float4 a0 = make_float4(0.f, 0.f, 0.f, 0.f);
      float4 a1 = a0, a2 = a0, a3 = a0;
      int e = e0;
      for (; e + 8 <= e1; e += 8) {           // 8 independent 8B loads in flight
        int s0 = stage[e + 0];
        int s1 = stage[e + 1];
        int s2 = stage[e + 2];
        int s3 = stage[e + 3];
        int s4 = stage[e + 4];
        int s5 = stage[e + 5];
        int s6 = stage[e + 6];
        int s7 = stage[e + 7];
        ushort4 u0 = ((const ushort4*)(xb + (size_t)s0 * DIM))[part];
        ushort4 u1 = ((const ushort4*)(xb + (size_t)s1 * DIM))[part];
        ushort4 u2 = ((const ushort4*)(xb + (size_t)s2 * DIM))[part];
        ushort4 u3 = ((const ushort4*)(xb + (size_t)s3 * DIM))[part];
        ushort4 u4 = ((const ushort4*)(xb + (size_t)s4 * DIM))[part];
        ushort4 u5 = ((const ushort4*)(xb + (size_t)s5 * DIM))[part];
        ushort4 u6 = ((const ushort4*)(xb + (size_t)s6 * DIM))[part];
        ushort4 u7 = ((const ushort4*)(xb + (size_t)s7 * DIM))[part];
        a0.x += bf16_to_f32(u0.x) + bf16_to_f32(u4.x);
        a0.y += bf16_to_f32(u0.y) + bf16_to_f32(u4.y);
        a0.z += bf16_to_f32(u0.z) + bf16_to_f32(u4.z);
        a0.w += bf16_to_f32(u0.w) + bf16_to_f32(u4.w);
        a1.x += bf16_to_f32(u1.x) + bf16_to_f32(u5.x);
        a1.y += bf16_to_f32(u1.y) + bf16_to_f32(u5.y);
        a1.z += bf16_to_f32(u1.z) + bf16_to_f32(u5.z);
        a1.w += bf16_to_f32(u1.w) + bf16_to_f32(u5.w);
        a2.x += bf16_to_f32(u2.x) + bf16_to_f32(u6.x);
        a2.y += bf16_to_f32(u2.y) + bf16_to_f32(u6.y);
        a2.z += bf16_to_f32(u2.z) + bf16_to_f32(u6.z);
        a2.w += bf16_to_f32(u2.w) + bf16_to_f32(u6.w);
        a3.x += bf16_to_f32(u3.x) + bf16_to_f32(u7.x);
        a3.y += bf16_to_f32(u3.y) + bf16_to_f32(u7.y);
        a3.z += bf16_to_f32(u3.z) + bf16_to_f32(u7.z);
        a3.w += bf16_to_f32(u3.w) + bf16_to_f32(u7.w);
      }
      for (; e + 4 <= e1; e += 4) {
        int s0 = stage[e + 0];
        int s1 = stage[e + 1];
        int s2 = stage[e + 2];
        int s3 = stage[e + 3];
        ushort4 u0 = ((const ushort4*)(xb + (size_t)s0 * DIM))[part];
        ushort4 u1 = ((const ushort4*)(xb + (size_t)s1 * DIM))[part];
        ushort4 u2 = ((const ushort4*)(xb + (size_t)s2 * DIM))[part];
        ushort4 u3 = ((const ushort4*)(xb + (size_t)s3 * DIM))[part];
        a0.x += bf16_to_f32(u0.x); a0.y += bf16_to_f32(u0.y);
        a0.z += bf16_to_f32(u0.z); a0.w += bf16_to_f32(u0.w);
        a1.x += bf16_to_f32(u1.x); a1.y += bf16_to_f32(u1.y);
        a1.z += bf16_to_f32(u1.z); a1.w += bf16_to_f32(u1.w);
        a2.x += bf16_to_f32(u2.x); a2.y += bf16_to_f32(u2.y);
        a2.z += bf16_to_f32(u2.z); a2.w += bf16_to_f32(u2.w);
        a3.x += bf16_to_f32(u3.x); a3.y += bf16_to_f32(u3.y);
        a3.z += bf16_to_f32(u3.z); a3.w += bf16_to_f32(u3.w);
      }
      for (; e < e1; ++e) {
        int s = stage[e];
        ushort4 u = ((const ushort4*)(xb + (size_t)s * DIM))[part];
        a0.x += bf16_to_f32(u.x); a0.y += bf16_to_f32(u.y);
        a0.z += bf16_to_f32(u.z); a0.w += bf16_to_f32(u.w);
      }
      ushort4 o;
      o.x = bf16_rne((a0.x + a1.x) + (a2.x + a3.x));
      o.y = bf16_rne((a0.y + a1.y) + (a2.y + a3.y));
      o.z = bf16_rne((a0.z + a1.z) + (a2.z + a3.z));
      o.w = bf16_rne((a0.w + a1.w) + (a2.w + a3.w));
      *(ushort4*)&hbuf[nl * HP + part * 4] = o;
    }
  }
  __syncthreads();
  // --- phase C: MFMA GEMM1 per wave + h1 store + BN stat partials ---
  {
    int wave = t >> 6;
    int lane = t & 63;
    int tile = b * 8 + wave;
    if (tile < NTILES) {
      int q = lane >> 4;
      int r16 = lane & 15;
      float onep = 1.0f + epsp[0];
      s16x8 bf[8];
#pragma unroll
      for (int f = 0; f < 8; ++f)
        bf[f] = ((const s16x8*)Wp)[f * 64 + lane];
      int lrow = wave * 16 + r16;             // local row in hbuf
      int grow = b * 128 + lrow;              // global row
      const s16x8* xrow = (const s16x8*)(xb + (size_t)grow * DIM);
      f32x4 acc[4] = {{0.f,0.f,0.f,0.f},{0.f,0.f,0.f,0.f},
                      {0.f,0.f,0.f,0.f},{0.f,0.f,0.f,0.f}};
#pragma unroll
      for (int kk = 0; kk < 2; ++kk) {
        s16x8 xv = xrow[kk * 4 + q];
        const unsigned short* hb = &hbuf[lrow * HP + kk * 32 + q * 8];
        ushort4 h0 = *(const ushort4*)hb;
        ushort4 h4 = *(const ushort4*)(hb + 4);
        s16x8 a;
        a[0] = (short)bf16_rne(fmaf(onep, bf16_to_f32((unsigned short)xv[0]), bf16_to_f32(h0.x)));
        a[1] = (short)bf16_rne(fmaf(onep, bf16_to_f32((unsigned short)xv[1]), bf16_to_f32(h0.y)));
        a[2] = (short)bf16_rne(fmaf(onep, bf16_to_f32((unsigned short)xv[2]), bf16_to_f32(h0.z)));
        a[3] = (short)bf16_rne(fmaf(onep, bf16_to_f32((unsigned short)xv[3]), bf16_to_f32(h0.w)));
        a[4] = (short)bf16_rne(fmaf(onep, bf16_to_f32((unsigned short)xv[4]), bf16_to_f32(h4.x)));
        a[5] = (short)bf16_rne(fmaf(onep, bf16_to_f32((unsigned short)xv[5]), bf16_to_f32(h4.y)));
        a[6] = (short)bf16_rne(fmaf(onep, bf16_to_f32((unsigned short)xv[6]), bf16_to_f32(h4.z)));
        a[7] = (short)bf16_rne(fmaf(onep, bf16_to_f32((unsigned short)xv[7]), bf16_to_f32(h4.w)));
#pragma unroll
        for (int nt = 0; nt < 4; ++nt)
          acc[nt] = __builtin_amdgcn_mfma_f32_16x16x32_bf16(
              a, bf[kk * 4 + nt], acc[nt], 0, 0, 0);
      }
      int orow = tile * 16 + q * 4;
#pragma unroll
      for (int nt = 0; nt < 4; ++nt) {
        int col = nt * 16 + r16;
        float bb = b1[col];
        float sl = 0.0f, ql = 0.0f;
#pragma unroll
        for (int r = 0; r < 4; ++r) {
          float v = acc[nt][r] + bb;
          h1[(size_t)(orow + r) * DIM + col] = v;
          sl += v;
          ql = fmaf(v, v, ql);
        }
        sl += __shfl_down(sl, 32); ql += __shfl_down(ql, 32);
        sl += __shfl_down(sl, 16); ql += __shfl_down(ql, 16);
        if (q == 0) {
          atomicAdd(&lsum[col], sl);
          atomicAdd(&lsq[col], ql);
        }
      }
    }
  }
  __syncthreads();
  if (t < DIM) {
    atomicAdd(&sums[t], lsum[t]);
    atomicAdd(&sumsq[t], lsq[t]);
  }
}

// ---------------- fused2 (MFMA): out = relu(bn(h1)) @ W2 + b2 ---------------
__global__ __launch_bounds__(256) void fused2_kernel(
    const float* __restrict__ h1, float* __restrict__ out,
    const unsigned short* __restrict__ Wp, const float* __restrict__ b2,
    const float* __restrict__ gamma, const float* __restrict__ beta,
    const float* __restrict__ sums, const float* __restrict__ sumsq) {
  __shared__ float sc_s[DIM];
  __shared__ float sh_s[DIM];
  int t = threadIdx.x;
  if (t < DIM) {
    float invN = 1.0f / (float)NNODES;
    float m = sums[t] * invN;
    float v = fmaf(-m, m, sumsq[t] * invN);
    float sc = gamma[t] * rsqrtf(v + 1e-5f);
    sc_s[t] = sc;
    sh_s[t] = fmaf(-m, sc, beta[t]);
  }
  __syncthreads();
  int wave = t >> 6;
  int lane = t & 63;
  int tile = blockIdx.x * 4 + wave;
  if (tile >= NTILES) return;
  int q = lane >> 4;
  int r16 = lane & 15;
  s16x8 bf[8];
#pragma unroll
  for (int f = 0; f < 8; ++f)
    bf[f] = ((const s16x8*)Wp)[f * 64 + lane];
  int arow = tile * 16 + r16;
  const float* hr = h1 + (size_t)arow * DIM + q * 8;
  f32x4 acc[4] = {{0.f,0.f,0.f,0.f},{0.f,0.f,0.f,0.f},
                  {0.f,0.f,0.f,0.f},{0.f,0.f,0.f,0.f}};
#pragma unroll
  for (int kk = 0; kk < 2; ++kk) {
    int kbase = kk * 32 + q * 8;
    float4 hv0 = *(const float4*)(hr + kk * 32);
    float4 hv1 = *(const float4*)(hr + kk * 32 + 4);
    float4 sc0 = *(const float4*)(sc_s + kbase);
    float4 sc1 = *(const float4*)(sc_s + kbase + 4);
    float4 sh0 = *(const float4*)(sh_s + kbase);
    float4 sh1 = *(const float4*)(sh_s + kbase + 4);
    s16x8 a;
    a[0] = (short)bf16_rne(fmaxf(fmaf(hv0.x, sc0.x, sh0.x), 0.f));
    a[1] = (short)bf16_rne(fmaxf(fmaf(hv0.y, sc0.y, sh0.y), 0.f));
    a[2] = (short)bf16_rne(fmaxf(fmaf(hv0.z, sc0.z, sh0.z), 0.f));
    a[3] = (short)bf16_rne(fmaxf(fmaf(hv0.w, sc0.w, sh0.w), 0.f));
    a[4] = (short)bf16_rne(fmaxf(fmaf(hv1.x, sc1.x, sh1.x), 0.f));
    a[5] = (short)bf16_rne(fmaxf(fmaf(hv1.y, sc1.y, sh1.y), 0.f));
    a[6] = (short)bf16_rne(fmaxf(fmaf(hv1.z, sc1.z, sh1.z), 0.f));
    a[7] = (short)bf16_rne(fmaxf(fmaf(hv1.w, sc1.w, sh1.w), 0.f));
#pragma unroll
    for (int nt = 0; nt < 4; ++nt)
      acc[nt] = __builtin_amdgcn_mfma_f32_16x16x32_bf16(
          a, bf[kk * 4 + nt], acc[nt], 0, 0, 0);
  }
  int orow = tile * 16 + q * 4;
#pragma unroll
  for (int nt = 0; nt < 4; ++nt) {
    int col = nt * 16 + r16;
    float bb = b2[col];
#pragma unroll
    for (int r = 0; r < 4; ++r)
      out[(size_t)(orow + r) * DIM + col] = acc[nt][r] + bb;
  }
}

extern "C" void kernel_launch(void* const* d_in, const int* in_sizes, int n_in,
                              void* d_out, int out_size, void* d_ws, size_t ws_size,
                              hipStream_t stream) {
  (void)in_sizes; (void)n_in; (void)out_size; (void)ws_size;
  const float* x     = (const float*)d_in[0];
  const int*   ei    = (const int*)d_in[1];
  const float* eps   = (const float*)d_in[2];
  const float* W1    = (const float*)d_in[3];
  const float* b1    = (const float*)d_in[4];
  const float* gamma = (const float*)d_in[5];
  const float* beta  = (const float*)d_in[6];
  const float* W2    = (const float*)d_in[7];
  const float* b2    = (const float*)d_in[8];
  float* outp = (float*)d_out;

  const int N = NNODES;

  // workspace (~25.7 MB)
  float* h1      = (float*)d_ws;                 // N*64 f32
  float* sums    = h1 + (size_t)N * DIM;         // 64 f32 (memset)
  float* sumsq   = sums + DIM;                   // 64 f32 (memset)
  int*   gcursor = (int*)(sumsq + DIM);          // NB int (memset, zero-based)
  unsigned short* Wp1 = (unsigned short*)(gcursor + 784); // 4096 bf16, 16B-aligned
  unsigned short* Wp2 = Wp1 + 4096;                       // 4096 bf16
  // d_out scratch (dead before fused2 overwrites it):
  //   bpart: NB*CAP ints = 12.41 MB ; xb: N*DIM bf16 = 12.80 MB (25.21<=25.6)
  int*            bpart = (int*)d_out;
  unsigned short* xb    = (unsigned short*)d_out + (size_t)NB * CAP * 2;

  // zero sums(64) + sumsq(64) + gcursor(NB) contiguous
  hipMemsetAsync(sums, 0, (2 * DIM + NB) * sizeof(int), stream);

  build_kernel<<<NPB + NCONV + 1, 1024, 0, stream>>>(x, ei, gcursor, xb, bpart,
                                                     W1, W2, Wp1, Wp2);
  mega_kernel <<<NB, 512, 0, stream>>>(bpart, gcursor, xb, h1,
                                       Wp1, b1, eps, sums, sumsq);
  fused2_kernel<<<(NTILES + 3) / 4, 256, 0, stream>>>(h1, outp, Wp2, b2,
                                                      gamma, beta, sums, sumsq);
}